// Round 4
// baseline (383.136 us; speedup 1.0000x reference)
//
#include <hip/hip_runtime.h>

// entmax-1.5 over rows of an 8192 x 4096 fp32 matrix, boolean mask (int32).
// R12: ONE WAVE = ONE ROW, zero barriers, 3-pass streaming.
//
// R9-R11 post-mortem: the 4-wave-gang-per-row design (R8, 117us) is
// gang-latency-bound -- all 4 waves rendezvous at phase barriers and run the
// solve REDUNDANTLY (4x VALU issue per row), so every latency chain (6-level
// shuffle reduces, 8x in the solve) stalls the whole block in lockstep. Three
// attempts to hide latency with ILP/prefetch (DPP R9, persistent-loop R10,
// straight-line 2-row R11) all failed the same way: the register allocator
// will not keep 32+ staged VGPRs live across barriers (R10 spilled, R11
// quietly refused: VGPR_Count=44 vs required ~80). So: get MLP from TLP.
//
// R12 structure (per wave, fully independent, NO s_barrier anywhere):
//   pass1: stream 32KB row (16 chunks x float4+int4), running max ->
//          6-shuffle butterfly -> thresh = mx-1 (tau* >= mx-1 always).
//   pass2: re-stream row (L2/L3-hot: re-read gap is ~us, data is within the
//          last few MB streamed -> 256MB L3 holds it) -> ballot-compact
//          candidates (z > thresh) into a WAVE-PRIVATE 384-slot LDS region.
//          64 ballot rounds, wave-uniform running count.
//   solve: exact piecewise-quadratic root iteration on 6 slots/lane
//          (stride-64: 2 lanes/bank = conflict-free), wave-local butterflies.
//          One wave solves one row ONCE (was: 4 waves x redundantly).
//   pass3: re-stream row -> p = relu(z - tau)^2 -> float4 stores.
//   CAP=384: #cand ~ #{s > smax-2} ~= 236 +- Gumbel tail for ~2048 unmasked
//   N(0,1); P(cnt>384) ~ 2e-5. Overflow (incl. all-masked rows) -> streaming
//   Newton fallback (correct, ~never taken).
// Occupancy is the point: no row staging -> small reg footprint, target 8
// waves/SIMD; 8 independent rows per SIMD at different phases fill each
// other's latency chains. LDS 4x384x4B = 6KB/block.

constexpr int NROWS  = 8192;
constexpr int NCOL   = 4096;
constexpr int NCHUNK = 16;    // row chunks: 64 lanes x 4 floats = 256/chunk
constexpr int CAP    = 384;   // candidate slots per wave (6 per lane)
constexpr int CPL    = 6;     // CAP / 64
constexpr int MAXIT  = 8;     // exact-quadratic solve cap (2-4 typical)

static __device__ __forceinline__ int mbcnt64(unsigned long long m) {
    // popcount of m restricted to lanes below this lane
    return __builtin_amdgcn_mbcnt_hi((unsigned)(m >> 32),
           __builtin_amdgcn_mbcnt_lo((unsigned)m, 0));
}

__global__ __launch_bounds__(256, 8)
void entmax15_kernel(const float* __restrict__ scores,
                     const int*   __restrict__ mask,
                     float*       __restrict__ out)
{
    __shared__ float cand[4 * CAP];   // wave w owns [w*CAP, (w+1)*CAP)

    const int tid  = threadIdx.x;
    const int lane = tid & 63;
    const int wave = tid >> 6;
    const int row  = blockIdx.x * 4 + wave;   // one wave per row

    const float* srow = scores + (size_t)row * NCOL;
    const int*   mrow = mask   + (size_t)row * NCOL;
    float*       orow = out    + (size_t)row * NCOL;

    // ---- pass 1: row max (streaming, nothing retained) ----
    float mx = -1e30f;
    #pragma unroll 4
    for (int c = 0; c < NCHUNK; ++c) {
        const int base = c * 256 + lane * 4;
        const float4 s4 = *reinterpret_cast<const float4*>(srow + base);
        const int4   m4 = *reinterpret_cast<const int4*>(mrow + base);
        const float z0 = m4.x ? s4.x * 0.5f : -5000.0f;
        const float z1 = m4.y ? s4.y * 0.5f : -5000.0f;
        const float z2 = m4.z ? s4.z * 0.5f : -5000.0f;
        const float z3 = m4.w ? s4.w * 0.5f : -5000.0f;
        mx = fmaxf(mx, fmaxf(fmaxf(z0, z1), fmaxf(z2, z3)));
    }
    #pragma unroll
    for (int off = 1; off < 64; off <<= 1)
        mx = fmaxf(mx, __shfl_xor(mx, off, 64));
    const float thresh = mx - 1.0f;   // tau* >= thresh: z <= thresh are dead

    // ---- sentinels for this wave's region (wave-private; no barrier) ----
    #pragma unroll
    for (int k = 0; k < CPL; ++k)
        cand[wave * CAP + k * 64 + lane] = -1e30f;

    // ---- pass 2: re-stream (L2/L3-hot) + ballot-compact candidates ----
    int cnt = 0;
    #pragma unroll 2
    for (int c = 0; c < NCHUNK; ++c) {
        const int base = c * 256 + lane * 4;
        const float4 s4 = *reinterpret_cast<const float4*>(srow + base);
        const int4   m4 = *reinterpret_cast<const int4*>(mrow + base);
        float zz[4];
        zz[0] = m4.x ? s4.x * 0.5f : -5000.0f;
        zz[1] = m4.y ? s4.y * 0.5f : -5000.0f;
        zz[2] = m4.z ? s4.z * 0.5f : -5000.0f;
        zz[3] = m4.w ? s4.w * 0.5f : -5000.0f;
        #pragma unroll
        for (int i = 0; i < 4; ++i) {
            const bool isc = zz[i] > thresh;
            const unsigned long long m = __ballot(isc);
            if (isc) {
                const int pos = cnt + mbcnt64(m);
                if (pos < CAP) cand[wave * CAP + pos] = zz[i];
            }
            cnt += (int)__popcll(m);  // wave-uniform
        }
    }

    float t = thresh;                 // left bracket: g(thresh) >= 0

    if (cnt <= CAP) {
        // ---- wave-local solve on 6 slots/lane (stride 64: 2 lanes/bank,
        // conflict-free; sentinels give d=0). Compiler inserts the lgkmcnt
        // wait between the compaction writes and these reads. ----
        float cv[CPL];
        #pragma unroll
        for (int k = 0; k < CPL; ++k)
            cv[k] = cand[wave * CAP + k * 64 + lane];

        // Exact piecewise-quadratic iteration: on the support at t,
        // s0 u^2 - 2 s1 u + (s2-1) = 0; u = (s1 - sqrt(disc))/s0 (smaller
        // root); disc<0 -> vertex jump; overshoot self-corrects (u<0).
        #pragma unroll 1
        for (int itr = 0; itr < MAXIT; ++itr) {
            float s0 = 0.f, s1 = 0.f, s2 = 0.f;
            #pragma unroll
            for (int k = 0; k < CPL; ++k) {
                const float d = fmaxf(cv[k] - t, 0.f);
                s2 = fmaf(d, d, s2);
                s1 += d;
                s0 += (d > 0.f) ? 1.0f : 0.0f;
            }
            #pragma unroll
            for (int off = 1; off < 64; off <<= 1) {
                s0 += __shfl_xor(s0, off, 64);
                s1 += __shfl_xor(s1, off, 64);
                s2 += __shfl_xor(s2, off, 64);
            }
            const float s0c  = fmaxf(s0, 1.0f);     // s0>=1 at t<=tau*<mx
            const float disc = fmaf(s1, s1, -s0c * (s2 - 1.0f));
            const float u    = (s1 - sqrtf(fmaxf(disc, 0.f))) / s0c;
            t += u;                                  // wave-uniform
            if (__builtin_fabsf(u) < 5e-7f) break;   // wave-uniform break
        }
    } else {
        // ---- fallback (P ~ 2e-5/row + all-masked rows): streaming Newton
        // on the full row (L2-hot re-reads). Monotone convergence from the
        // left bracket; block-free, wave-local. ----
        #pragma unroll 1
        for (int itr = 0; itr < 12; ++itr) {
            float s1 = 0.f, s2 = 0.f;
            #pragma unroll 2
            for (int c = 0; c < NCHUNK; ++c) {
                const int base = c * 256 + lane * 4;
                const float4 s4 = *reinterpret_cast<const float4*>(srow + base);
                const int4   m4 = *reinterpret_cast<const int4*>(mrow + base);
                float zz[4];
                zz[0] = m4.x ? s4.x * 0.5f : -5000.0f;
                zz[1] = m4.y ? s4.y * 0.5f : -5000.0f;
                zz[2] = m4.z ? s4.z * 0.5f : -5000.0f;
                zz[3] = m4.w ? s4.w * 0.5f : -5000.0f;
                #pragma unroll
                for (int i = 0; i < 4; ++i) {
                    const float d = fmaxf(zz[i] - t, 0.f);
                    s2 = fmaf(d, d, s2);
                    s1 += d;
                }
            }
            #pragma unroll
            for (int off = 1; off < 64; off <<= 1) {
                s1 += __shfl_xor(s1, off, 64);
                s2 += __shfl_xor(s2, off, 64);
            }
            const float step = (s2 - 1.0f) / (2.0f * fmaxf(s1, 1e-30f));
            t += step;                                  // wave-uniform
            if (__builtin_fabsf(step) < 5e-7f) break;   // wave-uniform
        }
    }

    // ---- pass 3: re-stream (L2/L3-hot) -> p = relu(z - tau)^2 -> store ----
    #pragma unroll 2
    for (int c = 0; c < NCHUNK; ++c) {
        const int base = c * 256 + lane * 4;
        const float4 s4 = *reinterpret_cast<const float4*>(srow + base);
        const int4   m4 = *reinterpret_cast<const int4*>(mrow + base);
        float4 o;
        float z, d;
        z = m4.x ? s4.x * 0.5f : -5000.0f; d = fmaxf(z - t, 0.f); o.x = d * d;
        z = m4.y ? s4.y * 0.5f : -5000.0f; d = fmaxf(z - t, 0.f); o.y = d * d;
        z = m4.z ? s4.z * 0.5f : -5000.0f; d = fmaxf(z - t, 0.f); o.z = d * d;
        z = m4.w ? s4.w * 0.5f : -5000.0f; d = fmaxf(z - t, 0.f); o.w = d * d;
        *reinterpret_cast<float4*>(orow + base) = o;
    }
}

extern "C" void kernel_launch(void* const* d_in, const int* in_sizes, int n_in,
                              void* d_out, int out_size, void* d_ws, size_t ws_size,
                              hipStream_t stream)
{
    const float* scores = (const float*)d_in[0];
    const int*   mask   = (const int*)d_in[1];
    float*       out    = (float*)d_out;

    dim3 grid(NROWS / 4);   // 4 rows per 256-thread block, one per wave
    dim3 block(256);
    hipLaunchKernelGGL(entmax15_kernel, grid, block, 0, stream,
                       scores, mask, out);
}

// Round 5
// 326.349 us; speedup vs baseline: 1.1740x; 1.1740x over previous
//
#include <hip/hip_runtime.h>

// entmax-1.5 over rows of an 8192 x 4096 fp32 matrix, boolean mask (int32).
// R13: SINGLE-PASS wave-per-row, zero barriers, candidate-carried output.
//
// R12 post-mortem: wave-per-row streamed at 2.84 TB/s (best of any round,
// VALU only 13.5%) but FETCH=402GB proved the pass-2/3 re-reads missed
// L2/L3 (2048 resident 32KB rows >> 4MB/XCD L2; aggregate stream overruns
// L3) -> 3x read traffic. The structure is right; the bytes are wrong.
//
// R13 moves the minimum: read scores+mask ONCE, write out ONCE.
//  * Single input pass with LAGGED-MAX compaction: insert z into the wave's
//    (value,col) candidate buffer if z > running_wave_max - 1; the wave max
//    is refreshed by butterfly every 4 chunks. Lagged max <= final max =>
//    threshold more permissive => superset of true candidates; stale entries
//    have z <= mx-1 <= t => d=0 in the solve => harmless. E[inserts] ~ 110-350
//    for ~2048 unmasked N(0,1); CAP=768 is >5-sigma headroom. Overflow
//    (incl. all-masked rows, where thr=-5001 admits everything) -> streaming
//    Newton fallback (R12-proven, ~never taken on this data).
//  * Output WITHOUT re-reading input: p!=0 only for z > tau >= mx-1 = exactly
//    the candidates. Zero-fill the row (full-line stores, no RMW fetch),
//    s_waitcnt vmcnt(0) (same-wave stores to same addr are unordered without
//    it), then scatter p=(cv-tau)^2 to candidate cols (hits just-dirtied L2).
//    Zero-fill issues BEFORE the solve so store latency hides under it.
//  * No s_barrier anywhere; wave-private LDS regions; vmcnt is wave-private.
// LDS: 4 waves x (768 x 4B val + 768 x 2B idx) = 18KB/block -> 8 blocks/CU
// (144KB of 160) at 8 waves/SIMD. Reg footprint ~45 VGPR (chunk temps +
// cv[12] + solve temps; no row staging -- the R10/R11 allocator trap avoided).

constexpr int NROWS  = 8192;
constexpr int NCOL   = 4096;
constexpr int NCHUNK = 16;    // row chunks: 64 lanes x 4 floats = 256/chunk
constexpr int CAP    = 768;   // candidate slots per wave
constexpr int CPL    = 12;    // CAP / 64
constexpr int MAXIT  = 8;     // exact-quadratic solve cap (2-4 typical)

static __device__ __forceinline__ int mbcnt64(unsigned long long m) {
    // popcount of m restricted to lanes below this lane
    return __builtin_amdgcn_mbcnt_hi((unsigned)(m >> 32),
           __builtin_amdgcn_mbcnt_lo((unsigned)m, 0));
}

__global__ __launch_bounds__(256, 8)
void entmax15_kernel(const float* __restrict__ scores,
                     const int*   __restrict__ mask,
                     float*       __restrict__ out)
{
    __shared__ float          cval[4 * CAP];  // wave w owns [w*CAP,(w+1)*CAP)
    __shared__ unsigned short cidx[4 * CAP];

    const int lane = threadIdx.x & 63;
    const int wave = threadIdx.x >> 6;
    const int row  = blockIdx.x * 4 + wave;   // one wave per row

    const float* srow = scores + (size_t)row * NCOL;
    const int*   mrow = mask   + (size_t)row * NCOL;
    float*       orow = out    + (size_t)row * NCOL;

    // Sentinels for this wave's value slots (wave-private; no barrier).
    #pragma unroll
    for (int k = 0; k < CPL; ++k)
        cval[wave * CAP + k * 64 + lane] = -1e30f;

    // ---- single input pass: running max + lagged-threshold compaction ----
    float ml  = -1e30f;   // per-lane running max
    float thr = 1e30f;    // wave-lagged insert threshold (refreshed below)
    int   cnt = 0;        // wave-uniform accepted-insert count

    #pragma unroll 4
    for (int c = 0; c < NCHUNK; ++c) {
        const int base = c * 256 + lane * 4;
        const float4 s4 = *reinterpret_cast<const float4*>(srow + base);
        const int4   m4 = *reinterpret_cast<const int4*>(mrow + base);
        float zz[4];
        zz[0] = m4.x ? s4.x * 0.5f : -5000.0f;
        zz[1] = m4.y ? s4.y * 0.5f : -5000.0f;
        zz[2] = m4.z ? s4.z * 0.5f : -5000.0f;
        zz[3] = m4.w ? s4.w * 0.5f : -5000.0f;
        ml = fmaxf(ml, fmaxf(fmaxf(zz[0], zz[1]), fmaxf(zz[2], zz[3])));

        if ((c & 3) == 0) {
            // Refresh wave max (includes this chunk: tighter, still <= final
            // max => still a superset threshold). 6-level butterfly.
            float w = ml;
            #pragma unroll
            for (int off = 1; off < 64; off <<= 1)
                w = fmaxf(w, __shfl_xor(w, off, 64));
            thr = w - 1.0f;
        }

        #pragma unroll
        for (int i = 0; i < 4; ++i) {
            const bool isc = zz[i] > thr;
            const unsigned long long m = __ballot(isc);
            if (isc) {
                const int pos = cnt + mbcnt64(m);
                if (pos < CAP) {
                    cval[wave * CAP + pos] = zz[i];
                    cidx[wave * CAP + pos] = (unsigned short)(base + i);
                }
            }
            cnt += (int)__popcll(m);  // wave-uniform
        }
    }

    // Exact row max -> thresh = mx - 1 (tau* >= thresh always).
    #pragma unroll
    for (int off = 1; off < 64; off <<= 1)
        ml = fmaxf(ml, __shfl_xor(ml, off, 64));
    float t = ml - 1.0f;              // left bracket: g(thresh) >= 0

    if (cnt <= CAP) {
        // ---- zero-fill output now: independent of tau; 16 full-line float4
        // store instrs fly under the solve (drained by vmcnt(0) below). ----
        #pragma unroll
        for (int c = 0; c < NCHUNK; ++c) {
            *reinterpret_cast<float4*>(orow + c * 256 + lane * 4) =
                make_float4(0.f, 0.f, 0.f, 0.f);
        }

        // ---- wave-local solve on 12 slots/lane (stride 64, 2 lanes/bank =
        // conflict-free; sentinels give d=0; stale candidates give d=0). ----
        float cv[CPL];
        #pragma unroll
        for (int k = 0; k < CPL; ++k)
            cv[k] = cval[wave * CAP + k * 64 + lane];

        // Exact piecewise-quadratic iteration: on the support at t,
        // s0 u^2 - 2 s1 u + (s2-1) = 0; u = (s1 - sqrt(disc))/s0 (smaller
        // root); disc<0 -> vertex jump; overshoot self-corrects (u<0).
        #pragma unroll 1
        for (int itr = 0; itr < MAXIT; ++itr) {
            float s0 = 0.f, s1 = 0.f, s2 = 0.f;
            #pragma unroll
            for (int k = 0; k < CPL; ++k) {
                const float d = fmaxf(cv[k] - t, 0.f);
                s2 = fmaf(d, d, s2);
                s1 += d;
                s0 += (d > 0.f) ? 1.0f : 0.0f;
            }
            #pragma unroll
            for (int off = 1; off < 64; off <<= 1) {
                s0 += __shfl_xor(s0, off, 64);
                s1 += __shfl_xor(s1, off, 64);
                s2 += __shfl_xor(s2, off, 64);
            }
            const float s0c  = fmaxf(s0, 1.0f);     // s0>=1 at t<=tau*<mx
            const float disc = fmaf(s1, s1, -s0c * (s2 - 1.0f));
            const float u    = (s1 - sqrtf(fmaxf(disc, 0.f))) / s0c;
            t += u;                                  // wave-uniform
            if (__builtin_fabsf(u) < 5e-7f) break;   // wave-uniform break
        }

        // ---- order zero-fill before scatter (same-wave stores to the same
        // address are NOT ordered without an explicit drain). ----
        asm volatile("s_waitcnt vmcnt(0)" ::: "memory");

        // ---- scatter: only support elements (d>0); lines are L2-dirty from
        // the zero-fill, so these dword stores are L2 hits. ----
        #pragma unroll
        for (int k = 0; k < CPL; ++k) {
            const float d = fmaxf(cv[k] - t, 0.f);
            if (d > 0.f) {
                const int col = (int)cidx[wave * CAP + k * 64 + lane];
                orow[col] = d * d;
            }
        }
    } else {
        // ---- fallback (overflow: pathological/all-masked rows; ~never on
        // this data): streaming Newton on the full row, then full output
        // pass. Re-reads are L2/L3-lottery but path is cold. ----
        #pragma unroll 1
        for (int itr = 0; itr < 12; ++itr) {
            float s1 = 0.f, s2 = 0.f;
            #pragma unroll 2
            for (int c = 0; c < NCHUNK; ++c) {
                const int base = c * 256 + lane * 4;
                const float4 s4 = *reinterpret_cast<const float4*>(srow + base);
                const int4   m4 = *reinterpret_cast<const int4*>(mrow + base);
                float zz[4];
                zz[0] = m4.x ? s4.x * 0.5f : -5000.0f;
                zz[1] = m4.y ? s4.y * 0.5f : -5000.0f;
                zz[2] = m4.z ? s4.z * 0.5f : -5000.0f;
                zz[3] = m4.w ? s4.w * 0.5f : -5000.0f;
                #pragma unroll
                for (int i = 0; i < 4; ++i) {
                    const float d = fmaxf(zz[i] - t, 0.f);
                    s2 = fmaf(d, d, s2);
                    s1 += d;
                }
            }
            #pragma unroll
            for (int off = 1; off < 64; off <<= 1) {
                s1 += __shfl_xor(s1, off, 64);
                s2 += __shfl_xor(s2, off, 64);
            }
            const float step = (s2 - 1.0f) / (2.0f * fmaxf(s1, 1e-30f));
            t += step;                                  // wave-uniform
            if (__builtin_fabsf(step) < 5e-7f) break;   // wave-uniform
        }
        #pragma unroll 2
        for (int c = 0; c < NCHUNK; ++c) {
            const int base = c * 256 + lane * 4;
            const float4 s4 = *reinterpret_cast<const float4*>(srow + base);
            const int4   m4 = *reinterpret_cast<const int4*>(mrow + base);
            float4 o;
            float z, d;
            z = m4.x ? s4.x * 0.5f : -5000.0f; d = fmaxf(z - t, 0.f); o.x = d * d;
            z = m4.y ? s4.y * 0.5f : -5000.0f; d = fmaxf(z - t, 0.f); o.y = d * d;
            z = m4.z ? s4.z * 0.5f : -5000.0f; d = fmaxf(z - t, 0.f); o.z = d * d;
            z = m4.w ? s4.w * 0.5f : -5000.0f; d = fmaxf(z - t, 0.f); o.w = d * d;
            *reinterpret_cast<float4*>(orow + base) = o;
        }
    }
}

extern "C" void kernel_launch(void* const* d_in, const int* in_sizes, int n_in,
                              void* d_out, int out_size, void* d_ws, size_t ws_size,
                              hipStream_t stream)
{
    const float* scores = (const float*)d_in[0];
    const int*   mask   = (const int*)d_in[1];
    float*       out    = (float*)d_out;

    dim3 grid(NROWS / 4);   // 4 rows per 256-thread block, one per wave
    dim3 block(256);
    hipLaunchKernelGGL(entmax15_kernel, grid, block, 0, stream,
                       scores, mask, out);
}

// Round 6
// 319.816 us; speedup vs baseline: 1.1980x; 1.0204x over previous
//
#include <hip/hip_runtime.h>

// entmax-1.5 over rows of an 8192 x 4096 fp32 matrix, boolean mask (int32).
// R14: R13 single-pass wave-per-row (FETCH-proven minimal: 131GB read-once,
// candidate-carried output, zero barriers) + EXPLICIT LOAD DOUBLE-BUFFER.
//
// R13 post-mortem: traffic minimal but dur 125us at 2.2TB/s, VALUBusy 16%,
// VGPR=32. 8 waves/SIMD x 37k cy/row ~= 60 VMEM x ~500cy => per-wave loads
// effectively SERIAL: the compiler staged ~1 chunk; ballot/insert code (exec
// mask ops, LDS writes, shuffle refreshes) sat between load issue and next
// load issue. Little's law: ~2KB in flight/wave x 5.4 waves -> 2.2TB/s, QED.
//
// Fix: fully-unrolled 2-chunk-group double buffer -- group g+1's 4 loads
// (float4+int4 x2) ISSUE before group g is processed; first use (cndmask)
// is where the vmcnt wait lands, so ~300cy of process overlaps ~500cy of
// latency, x ~6 waves/SIMD. Unlike R10/R11's failed staging, there is NO
// barrier here (the proven allocator-killer was live ranges crossing asm
// barriers); this is straight-line unrolled code.
// __launch_bounds__(256,6): staging 32 + misc ~30 => ~65 VGPR peak, cap 85
// (never force the 64-cap of 8 waves/SIMD -- spill is the proven failure).
// LDS 18KB/block (unchanged) allows 6 blocks/CU at 6 waves/SIMD.

constexpr int NROWS  = 8192;
constexpr int NCOL   = 4096;
constexpr int NCHUNK = 16;    // row chunks: 64 lanes x 4 floats = 256/chunk
constexpr int CAP    = 768;   // candidate slots per wave (R13: ~550 expected)
constexpr int CPL    = 12;    // CAP / 64
constexpr int MAXIT  = 8;     // exact-quadratic solve cap (2-4 typical)

static __device__ __forceinline__ int mbcnt64(unsigned long long m) {
    // popcount of m restricted to lanes below this lane
    return __builtin_amdgcn_mbcnt_hi((unsigned)(m >> 32),
           __builtin_amdgcn_mbcnt_lo((unsigned)m, 0));
}

__global__ __launch_bounds__(256, 6)
void entmax15_kernel(const float* __restrict__ scores,
                     const int*   __restrict__ mask,
                     float*       __restrict__ out)
{
    __shared__ float          cval[4 * CAP];  // wave w owns [w*CAP,(w+1)*CAP)
    __shared__ unsigned short cidx[4 * CAP];

    const int lane = threadIdx.x & 63;
    const int wave = threadIdx.x >> 6;
    const int row  = blockIdx.x * 4 + wave;   // one wave per row

    const float* srow = scores + (size_t)row * NCOL;
    const int*   mrow = mask   + (size_t)row * NCOL;
    float*       orow = out    + (size_t)row * NCOL;

    // Sentinels for this wave's value slots (wave-private; no barrier).
    #pragma unroll
    for (int k = 0; k < CPL; ++k)
        cval[wave * CAP + k * 64 + lane] = -1e30f;

    // ---- single input pass: double-buffered 2-chunk groups ----
    float ml  = -1e30f;   // per-lane running max
    float thr = 1e30f;    // wave-lagged insert threshold
    int   cnt = 0;        // wave-uniform accepted-insert count

    float4 sA[2], sB[2];
    int4   mA[2], mB[2];

    // Issue group g's 4 loads (2 chunks). Pure issue; no dependent use here.
    auto LOADG = [&](int g, float4 (&s)[2], int4 (&m)[2]) {
        #pragma unroll
        for (int j = 0; j < 2; ++j) {
            const int base = (g * 2 + j) * 256 + lane * 4;
            s[j] = *reinterpret_cast<const float4*>(srow + base);
            m[j] = *reinterpret_cast<const int4*>(mrow + base);
        }
    };

    // Process group g from staged regs: mask-select, running max, lagged-thr
    // refresh (chunks 0/4/8/12: butterfly incl. current chunk -> tighter,
    // still <= final max => superset threshold; stale entries die in the
    // solve via d=0), ballot-compact (value,col) into the wave's region.
    auto PROCG = [&](int g, const float4 (&s)[2], const int4 (&m)[2]) {
        #pragma unroll
        for (int j = 0; j < 2; ++j) {
            const int c    = g * 2 + j;
            const int base = c * 256 + lane * 4;
            float zz[4];
            zz[0] = m[j].x ? s[j].x * 0.5f : -5000.0f;
            zz[1] = m[j].y ? s[j].y * 0.5f : -5000.0f;
            zz[2] = m[j].z ? s[j].z * 0.5f : -5000.0f;
            zz[3] = m[j].w ? s[j].w * 0.5f : -5000.0f;
            ml = fmaxf(ml, fmaxf(fmaxf(zz[0], zz[1]), fmaxf(zz[2], zz[3])));

            if ((c & 3) == 0) {       // refresh wave threshold
                float w = ml;
                #pragma unroll
                for (int off = 1; off < 64; off <<= 1)
                    w = fmaxf(w, __shfl_xor(w, off, 64));
                thr = w - 1.0f;
            }

            #pragma unroll
            for (int i = 0; i < 4; ++i) {
                const bool isc = zz[i] > thr;
                const unsigned long long bm = __ballot(isc);
                if (isc) {
                    const int pos = cnt + mbcnt64(bm);
                    if (pos < CAP) {
                        cval[wave * CAP + pos] = zz[i];
                        cidx[wave * CAP + pos] = (unsigned short)(base + i);
                    }
                }
                cnt += (int)__popcll(bm);  // wave-uniform
            }
        }
    };

    // Straight-line software pipeline: loads of g+1 issue before PROC(g).
    LOADG(0, sA, mA);
    LOADG(1, sB, mB); PROCG(0, sA, mA);
    LOADG(2, sA, mA); PROCG(1, sB, mB);
    LOADG(3, sB, mB); PROCG(2, sA, mA);
    LOADG(4, sA, mA); PROCG(3, sB, mB);
    LOADG(5, sB, mB); PROCG(4, sA, mA);
    LOADG(6, sA, mA); PROCG(5, sB, mB);
    LOADG(7, sB, mB); PROCG(6, sA, mA);
                      PROCG(7, sB, mB);

    // Exact row max -> left bracket t = mx - 1 (tau* >= mx - 1 always).
    #pragma unroll
    for (int off = 1; off < 64; off <<= 1)
        ml = fmaxf(ml, __shfl_xor(ml, off, 64));
    float t = ml - 1.0f;

    if (cnt <= CAP) {
        // Zero-fill output now: independent of tau; 16 full-line float4
        // stores fly under the solve (drained by vmcnt(0) below).
        #pragma unroll
        for (int c = 0; c < NCHUNK; ++c) {
            *reinterpret_cast<float4*>(orow + c * 256 + lane * 4) =
                make_float4(0.f, 0.f, 0.f, 0.f);
        }

        // Wave-local solve on 12 slots/lane (stride 64: 2 lanes/bank =
        // conflict-free; sentinels/stale entries give d=0).
        float cv[CPL];
        #pragma unroll
        for (int k = 0; k < CPL; ++k)
            cv[k] = cval[wave * CAP + k * 64 + lane];

        // Exact piecewise-quadratic iteration: on the support at t,
        // s0 u^2 - 2 s1 u + (s2-1) = 0; u = (s1 - sqrt(disc))/s0 (smaller
        // root); disc<0 -> vertex jump; overshoot self-corrects (u<0).
        #pragma unroll 1
        for (int itr = 0; itr < MAXIT; ++itr) {
            float s0 = 0.f, s1 = 0.f, s2 = 0.f;
            #pragma unroll
            for (int k = 0; k < CPL; ++k) {
                const float d = fmaxf(cv[k] - t, 0.f);
                s2 = fmaf(d, d, s2);
                s1 += d;
                s0 += (d > 0.f) ? 1.0f : 0.0f;
            }
            #pragma unroll
            for (int off = 1; off < 64; off <<= 1) {
                s0 += __shfl_xor(s0, off, 64);
                s1 += __shfl_xor(s1, off, 64);
                s2 += __shfl_xor(s2, off, 64);
            }
            const float s0c  = fmaxf(s0, 1.0f);     // s0>=1 at t<=tau*<mx
            const float disc = fmaf(s1, s1, -s0c * (s2 - 1.0f));
            const float u    = (s1 - sqrtf(fmaxf(disc, 0.f))) / s0c;
            t += u;                                  // wave-uniform
            if (__builtin_fabsf(u) < 5e-7f) break;   // wave-uniform break
        }

        // Order zero-fill before scatter (same-wave stores to the same
        // address are NOT ordered without an explicit drain).
        asm volatile("s_waitcnt vmcnt(0)" ::: "memory");

        // Scatter: only support elements (d>0); lines are L2-dirty from the
        // zero-fill, so these dword stores are L2 hits.
        #pragma unroll
        for (int k = 0; k < CPL; ++k) {
            const float d = fmaxf(cv[k] - t, 0.f);
            if (d > 0.f) {
                const int col = (int)cidx[wave * CAP + k * 64 + lane];
                orow[col] = d * d;
            }
        }
    } else {
        // Fallback (overflow: pathological/all-masked rows; ~never on this
        // data): streaming Newton on the full row, then full output pass.
        #pragma unroll 1
        for (int itr = 0; itr < 12; ++itr) {
            float s1 = 0.f, s2 = 0.f;
            #pragma unroll 2
            for (int c = 0; c < NCHUNK; ++c) {
                const int base = c * 256 + lane * 4;
                const float4 s4 = *reinterpret_cast<const float4*>(srow + base);
                const int4   m4 = *reinterpret_cast<const int4*>(mrow + base);
                float zz[4];
                zz[0] = m4.x ? s4.x * 0.5f : -5000.0f;
                zz[1] = m4.y ? s4.y * 0.5f : -5000.0f;
                zz[2] = m4.z ? s4.z * 0.5f : -5000.0f;
                zz[3] = m4.w ? s4.w * 0.5f : -5000.0f;
                #pragma unroll
                for (int i = 0; i < 4; ++i) {
                    const float d = fmaxf(zz[i] - t, 0.f);
                    s2 = fmaf(d, d, s2);
                    s1 += d;
                }
            }
            #pragma unroll
            for (int off = 1; off < 64; off <<= 1) {
                s1 += __shfl_xor(s1, off, 64);
                s2 += __shfl_xor(s2, off, 64);
            }
            const float step = (s2 - 1.0f) / (2.0f * fmaxf(s1, 1e-30f));
            t += step;                                  // wave-uniform
            if (__builtin_fabsf(step) < 5e-7f) break;   // wave-uniform
        }
        #pragma unroll 2
        for (int c = 0; c < NCHUNK; ++c) {
            const int base = c * 256 + lane * 4;
            const float4 s4 = *reinterpret_cast<const float4*>(srow + base);
            const int4   m4 = *reinterpret_cast<const int4*>(mrow + base);
            float4 o;
            float z, d;
            z = m4.x ? s4.x * 0.5f : -5000.0f; d = fmaxf(z - t, 0.f); o.x = d * d;
            z = m4.y ? s4.y * 0.5f : -5000.0f; d = fmaxf(z - t, 0.f); o.y = d * d;
            z = m4.z ? s4.z * 0.5f : -5000.0f; d = fmaxf(z - t, 0.f); o.z = d * d;
            z = m4.w ? s4.w * 0.5f : -5000.0f; d = fmaxf(z - t, 0.f); o.w = d * d;
            *reinterpret_cast<float4*>(orow + base) = o;
        }
    }
}

extern "C" void kernel_launch(void* const* d_in, const int* in_sizes, int n_in,
                              void* d_out, int out_size, void* d_ws, size_t ws_size,
                              hipStream_t stream)
{
    const float* scores = (const float*)d_in[0];
    const int*   mask   = (const int*)d_in[1];
    float*       out    = (float*)d_out;

    dim3 grid(NROWS / 4);   // 4 rows per 256-thread block, one per wave
    dim3 block(256);
    hipLaunchKernelGGL(entmax15_kernel, grid, block, 0, stream,
                       scores, mask, out);
}